// Round 2
// baseline (584.166 us; speedup 1.0000x reference)
//
#include <hip/hip_runtime.h>
#include <hip/hip_bf16.h>
#include <stdint.h>

typedef __hip_bfloat16 bf16;
typedef __attribute__((ext_vector_type(8))) short short8;
typedef __attribute__((ext_vector_type(4))) float f32x4;

#define NB 32768
#define NC 1024
#define NH 1024
#define NS 8
#define NDC 64
#define MAXBLK 520   // max routed-GEMM blocks: 32768/64 + 8 styles' partial blocks

__device__ __forceinline__ void gload_lds16(const void* g, void* l) {
    __builtin_amdgcn_global_load_lds((const __attribute__((address_space(1))) void*)g,
                                     (__attribute__((address_space(3))) void*)l, 16, 0, 0);
}

__device__ __forceinline__ short f2bf(float x) {
    bf16 h = __float2bfloat16(x);
    short s;
    __builtin_memcpy(&s, &h, 2);
    return s;
}

// ---------------- fp32 -> bf16 bulk convert (8 elems/thread) ----------------
__global__ __launch_bounds__(256) void convert_kernel(
    const float* __restrict__ in, bf16* __restrict__ out)
{
    const size_t i = ((size_t)blockIdx.x * 256 + threadIdx.x) * 8;
    float4 a = *(const float4*)(in + i);
    float4 b = *(const float4*)(in + i + 4);
    short8 v;
    v[0] = f2bf(a.x); v[1] = f2bf(a.y); v[2] = f2bf(a.z); v[3] = f2bf(a.w);
    v[4] = f2bf(b.x); v[5] = f2bf(b.y); v[6] = f2bf(b.z); v[7] = f2bf(b.w);
    *(short8*)((short*)out + i) = v;
}

// ---------------- batched tiled transpose + downcast: out[c][r] = bf16(in[r][c]) ----------------
__global__ __launch_bounds__(256) void transpose_kernel(
    const float* __restrict__ in, bf16* __restrict__ out,
    int R, int Ccols, long long in_bs, long long out_bs)
{
    __shared__ float tile[32][33];
    const float* inb = in + (long long)blockIdx.z * in_bs;
    bf16* outb = out + (long long)blockIdx.z * out_bs;
    int c0 = blockIdx.x * 32, r0 = blockIdx.y * 32;
    int tx = threadIdx.x, ty = threadIdx.y; // 32 x 8
#pragma unroll
    for (int i = 0; i < 32; i += 8)
        tile[ty + i][tx] = inb[(size_t)(r0 + ty + i) * Ccols + c0 + tx];
    __syncthreads();
#pragma unroll
    for (int i = 0; i < 32; i += 8)
        outb[(size_t)(c0 + ty + i) * R + r0 + tx] = __float2bfloat16(tile[tx][ty + i]);
}

// ---------------- style_contrib split-K stage 1 ----------------
__global__ __launch_bounds__(256) void style_partial_kernel(
    const float* __restrict__ style_emb, const float* __restrict__ Wa1,
    float* __restrict__ partial)
{
    const int h = (blockIdx.x & 3) * 256 + threadIdx.x;
    const int ks = blockIdx.x >> 2;
    float acc[NS];
#pragma unroll
    for (int s = 0; s < NS; ++s) acc[s] = 0.f;
#pragma unroll
    for (int kk = 0; kk < 16; ++kk) {
        const int k = ks * 16 + kk;
        const float w = Wa1[(size_t)(NC + k) * NH + h];
#pragma unroll
        for (int s = 0; s < NS; ++s)
            acc[s] += style_emb[s * NH + k] * w;
    }
#pragma unroll
    for (int s = 0; s < NS; ++s)
        partial[((size_t)ks * NS + s) * NH + h] = acc[s];
}

// ---------------- style_contrib split-K stage 2 ----------------
__global__ __launch_bounds__(256) void style_reduce_kernel(
    const float* __restrict__ partial, const float* __restrict__ ba1,
    float* __restrict__ out)
{
    const int i = blockIdx.x * 256 + threadIdx.x; // 8192 = NS*NH
    const int h = i & (NH - 1);
    const int s = i >> 10;
    float acc = ba1[h];
#pragma unroll 8
    for (int ks = 0; ks < 64; ++ks)
        acc += partial[((size_t)ks * NS + s) * NH + h];
    out[i] = acc;
}

// ---------------- 2-phase prefetch bf16 GEMM: C = epilogue(A(MxK) @ BT(NxK)^T) ----------------
// MODE 0: bf16 out = relu(acc + style_contrib[style_idx[row]][col])     -> hidden
// MODE 1: f32  out = acc + resid[row][col] + bias[col]                  -> adjusted_logits
// T3-minimum schedule: stage tile t+1 BEFORE computing tile t; the compiler's
// vmcnt(0) at the single __syncthreads then lands after a full compute phase.
template<int MODE>
__global__ __launch_bounds__(256, 2) void gemm_kernel(
    const bf16* __restrict__ A, const bf16* __restrict__ BT,
    bf16* __restrict__ Cb, float* __restrict__ Cf,
    int N, int K,
    const float* __restrict__ style_contrib, const int* __restrict__ style_idx,
    const float* __restrict__ resid, const float* __restrict__ bias)
{
    __shared__ short lA[2][128 * 32];   // 2 x 8 KB
    __shared__ short lB[2][128 * 32];   // 2 x 8 KB

    const int t = threadIdx.x;
    const int lane = t & 63;
    const int wave = t >> 6;
    const int wr = wave >> 1;
    const int wc = wave & 1;

    // T1: XCD-aware bijective swizzle (8 XCDs; nwg = 2048, divisible by 8).
    const int nwg = gridDim.x * gridDim.y;
    const int flat = blockIdx.y * gridDim.x + blockIdx.x;
    const int cpx = nwg >> 3;
    const int swz = (flat & 7) * cpx + (flat >> 3);
    const int bm0 = (swz / gridDim.x) * 128;
    const int bn0 = (swz % gridDim.x) * 128;

    const int r0 = t >> 2;        // staging row
    const int c8 = (t & 3) * 8;   // staging k-chunk

    const int mrow = lane & 15;
    const int quad = lane >> 4;

    f32x4 acc[4][4];
#pragma unroll
    for (int i = 0; i < 4; ++i)
#pragma unroll
        for (int j = 0; j < 4; ++j) acc[i][j] = (f32x4){0.f, 0.f, 0.f, 0.f};

    const bf16* gA = A + (size_t)(bm0 + r0) * K + c8;
    const bf16* gB = BT + (size_t)(bn0 + r0) * K + c8;

    // prologue: stage tile 0 into buf 0
    gload_lds16(gA, lA[0] + t * 8);
    gload_lds16(gA + (size_t)64 * K, lA[0] + 2048 + t * 8);
    gload_lds16(gB, lB[0] + t * 8);
    gload_lds16(gB + (size_t)64 * K, lB[0] + 2048 + t * 8);
    __syncthreads();

    int cur = 0;
    for (int k0 = 0; k0 < K; k0 += 32) {
        const int nxt = cur ^ 1;
        if (k0 + 32 < K) {   // issue NEXT tile first (overlaps with compute below)
            gload_lds16(gA + k0 + 32, lA[nxt] + t * 8);
            gload_lds16(gA + (size_t)64 * K + k0 + 32, lA[nxt] + 2048 + t * 8);
            gload_lds16(gB + k0 + 32, lB[nxt] + t * 8);
            gload_lds16(gB + (size_t)64 * K + k0 + 32, lB[nxt] + 2048 + t * 8);
        }

        short8 af[4], bfr[4];
#pragma unroll
        for (int i = 0; i < 4; ++i)
            af[i] = *(const short8*)(lA[cur] + (wr * 64 + i * 16 + mrow) * 32 + quad * 8);
#pragma unroll
        for (int j = 0; j < 4; ++j)
            bfr[j] = *(const short8*)(lB[cur] + (wc * 64 + j * 16 + mrow) * 32 + quad * 8);
#pragma unroll
        for (int i = 0; i < 4; ++i)
#pragma unroll
            for (int j = 0; j < 4; ++j)
                acc[i][j] = __builtin_amdgcn_mfma_f32_16x16x32_bf16(af[i], bfr[j], acc[i][j], 0, 0, 0);

        __syncthreads();   // drains vmcnt(0): next tile landed; also protects WAR on buf[nxt]
        cur = nxt;
    }

    // epilogue: C/D layout col = lane&15, row = quad*4 + reg
#pragma unroll
    for (int i = 0; i < 4; ++i) {
#pragma unroll
        for (int r = 0; r < 4; ++r) {
            const int grow = bm0 + wr * 64 + i * 16 + quad * 4 + r;
            const float* scrow = nullptr;
            const float* resrow = nullptr;
            if (MODE == 0) scrow = style_contrib + (size_t)style_idx[grow] * N;
            if (MODE == 1) resrow = resid + (size_t)grow * N;
#pragma unroll
            for (int j = 0; j < 4; ++j) {
                const int gcol = bn0 + wc * 64 + j * 16 + mrow;
                float v = acc[i][j][r];
                if (MODE == 0) {
                    v += scrow[gcol];
                    v = fmaxf(v, 0.f);
                    Cb[(size_t)grow * N + gcol] = __float2bfloat16(v);
                } else {
                    v += resrow[gcol] + bias[gcol];
                    Cf[(size_t)grow * N + gcol] = v;
                }
            }
        }
    }
}

// ---------------- row softmax (1024 cols), f32 in -> bf16 out ----------------
__global__ __launch_bounds__(256) void softmax_kernel(
    const float* __restrict__ in, bf16* __restrict__ out)
{
    const size_t row = blockIdx.x;
    const float* x = in + row * NC;
    bf16* o = out + row * NC;
    const int t = threadIdx.x;
    __shared__ float red[8];

    float v[4];
    float m = -1e30f;
#pragma unroll
    for (int i = 0; i < 4; ++i) {
        v[i] = x[t + i * 256];
        m = fmaxf(m, v[i]);
    }
#pragma unroll
    for (int off = 1; off < 64; off <<= 1) m = fmaxf(m, __shfl_xor(m, off, 64));
    const int wv = t >> 6;
    if ((t & 63) == 0) red[wv] = m;
    __syncthreads();
    const float gm = fmaxf(fmaxf(red[0], red[1]), fmaxf(red[2], red[3]));

    float s = 0.f;
#pragma unroll
    for (int i = 0; i < 4; ++i) {
        v[i] = __expf(v[i] - gm);
        s += v[i];
    }
#pragma unroll
    for (int off = 1; off < 64; off <<= 1) s += __shfl_xor(s, off, 64);
    if ((t & 63) == 0) red[4 + wv] = s;
    __syncthreads();
    const float inv = 1.0f / (red[4] + red[5] + red[6] + red[7]);
#pragma unroll
    for (int i = 0; i < 4; ++i) o[t + i * 256] = __float2bfloat16(v[i] * inv);
}

// ================= style-routed calibrator =================

// per-block histogram of styles
__global__ __launch_bounds__(256) void hist_kernel(
    const int* __restrict__ idx, int* __restrict__ cnt)
{
    __shared__ int h[NS];
    if (threadIdx.x < NS) h[threadIdx.x] = 0;
    __syncthreads();
    atomicAdd(&h[idx[blockIdx.x * 256 + threadIdx.x]], 1);
    __syncthreads();
    if (threadIdx.x < NS) atomicAdd(&cnt[threadIdx.x], h[threadIdx.x]);
}

// single-thread plan: style segment bases + 64-row block table
__global__ void plan_kernel(const int* __restrict__ cnt, int* __restrict__ cursor,
                            int* __restrict__ blk_style, int* __restrict__ blk_seg0,
                            int* __restrict__ blk_nv)
{
    if (threadIdx.x != 0 || blockIdx.x != 0) return;
    int base = 0, nb = 0;
    for (int s = 0; s < NS; ++s) {
        cursor[s] = base;
        const int c = cnt[s];
        for (int i = 0; i < c; i += 64) {
            blk_style[nb] = s;
            blk_seg0[nb] = base + i;
            blk_nv[nb] = min(64, c - i);
            ++nb;
        }
        base += c;
    }
    for (int b = nb; b < MAXBLK; ++b) { blk_style[b] = 0; blk_seg0[b] = 0; blk_nv[b] = 0; }
}

// scatter rows into style-sorted order (wave-aggregated atomics: 8/wave)
__global__ __launch_bounds__(256) void scatter_kernel(
    const int* __restrict__ idx, int* __restrict__ cursor, int* __restrict__ order)
{
    const int b = blockIdx.x * 256 + threadIdx.x;
    const int s = idx[b];
    const int lane = threadIdx.x & 63;
    int pos = 0;
#pragma unroll 1
    for (int ss = 0; ss < NS; ++ss) {
        const unsigned long long m = __ballot(s == ss);  // wave-uniform
        if (m == 0ull) continue;
        const int leader = __ffsll(m) - 1;
        int base = 0;
        if (lane == leader) base = atomicAdd(&cursor[ss], __popcll(m));
        base = __shfl(base, leader, 64);
        if (s == ss)
            pos = base + __popcll(m & ((1ull << lane) - 1ull));
    }
    order[pos] = b;
}

// routed GEMM: 64 gathered rows x 64 cols (one style per block), K=1024,
// 2-phase prefetch dbuf; fused epilogue: relu(+bc1) -> dot Wc2 -> +bc2 -> sigmoid
__global__ __launch_bounds__(256, 2) void gemm_cal_kernel(
    const bf16* __restrict__ probs, const bf16* __restrict__ Wc1T,
    const int* __restrict__ order, const int* __restrict__ blk_style,
    const int* __restrict__ blk_seg0, const int* __restrict__ blk_nv,
    const float* __restrict__ bc1, const float* __restrict__ Wc2,
    const float* __restrict__ bc2, float* __restrict__ conf_out)
{
    const int nv = blk_nv[blockIdx.x];
    if (nv == 0) return;
    const int s = blk_style[blockIdx.x];
    const int seg0 = blk_seg0[blockIdx.x];

    __shared__ short lA[2][64 * 32];  // 2 x 4 KB gathered probs tiles
    __shared__ short lB[2][64 * 32];  // 2 x 4 KB Wc1T tiles
    __shared__ int rid[64];

    const int t = threadIdx.x;
    const int lane = t & 63;
    const int wave = t >> 6;

    if (t < 64) rid[t] = order[seg0 + min(t, nv - 1)];  // pad rows: clamp (benign dup)
    __syncthreads();

    const int r0 = t >> 2, c8 = (t & 3) * 8;
    // per-lane GLOBAL source with linear LDS dest is the legal gather form
    const bf16* gA = probs + (size_t)rid[r0] * NC + c8;
    const bf16* gB = Wc1T + ((size_t)s * NDC + r0) * NC + c8;

    const int mrow = lane & 15;
    const int quad = lane >> 4;

    f32x4 acc[4];
#pragma unroll
    for (int j = 0; j < 4; ++j) acc[j] = (f32x4){0.f, 0.f, 0.f, 0.f};

    // prologue: stage tile 0
    gload_lds16(gA, lA[0] + t * 8);
    gload_lds16(gB, lB[0] + t * 8);
    __syncthreads();

    int cur = 0;
    for (int k0 = 0; k0 < NC; k0 += 32) {
        const int nxt = cur ^ 1;
        if (k0 + 32 < NC) {
            gload_lds16(gA + k0 + 32, lA[nxt] + t * 8);
            gload_lds16(gB + k0 + 32, lB[nxt] + t * 8);
        }

        // wave computes rows wave*16..wave*16+15, all 64 cols
        const short8 af = *(const short8*)(lA[cur] + (wave * 16 + mrow) * 32 + quad * 8);
        short8 bfr[4];
#pragma unroll
        for (int j = 0; j < 4; ++j)
            bfr[j] = *(const short8*)(lB[cur] + (j * 16 + mrow) * 32 + quad * 8);
#pragma unroll
        for (int j = 0; j < 4; ++j)
            acc[j] = __builtin_amdgcn_mfma_f32_16x16x32_bf16(af, bfr[j], acc[j], 0, 0, 0);

        __syncthreads();
        cur = nxt;
    }

    // epilogue: col d = j*16+mrow, local row = wave*16 + quad*4 + r
    float bcv[4], wcv[4];
#pragma unroll
    for (int j = 0; j < 4; ++j) {
        const int d = j * 16 + mrow;
        bcv[j] = bc1[s * NDC + d];
        wcv[j] = Wc2[s * NDC + d];
    }
    const float bias2 = bc2[s];
#pragma unroll
    for (int r = 0; r < 4; ++r) {
        float p = 0.f;
#pragma unroll
        for (int j = 0; j < 4; ++j) {
            const float v = acc[j][r] + bcv[j];
            p += fmaxf(v, 0.f) * wcv[j];
        }
#pragma unroll
        for (int off = 1; off < 16; off <<= 1) p += __shfl_xor(p, off, 64);
        const int lrow = wave * 16 + quad * 4 + r;
        if (mrow == 0 && lrow < nv)
            conf_out[rid[lrow]] = 1.0f / (1.0f + __expf(-(p + bias2)));
    }
}

extern "C" void kernel_launch(void* const* d_in, const int* in_sizes, int n_in,
                              void* d_out, int out_size, void* d_ws, size_t ws_size,
                              hipStream_t stream) {
    const float* logits    = (const float*)d_in[0];
    const int*   style_idx = (const int*)d_in[1];
    const float* style_emb = (const float*)d_in[2];
    const float* Wa1       = (const float*)d_in[3];
    const float* ba1       = (const float*)d_in[4];
    const float* Wa2       = (const float*)d_in[5];
    const float* ba2       = (const float*)d_in[6];
    const float* Wc1       = (const float*)d_in[7];
    const float* bc1       = (const float*)d_in[8];
    const float* Wc2       = (const float*)d_in[9];
    const float* bc2       = (const float*)d_in[10];

    char* ws = (char*)d_ws;
    bf16* logits_b = (bf16*)ws;        ws += (size_t)NB * NC * 2;          // 64 MB
    bf16* hidden = (bf16*)ws;          ws += (size_t)NB * NH * 2;          // 64 MB (reused as probs)
    bf16* W1T = (bf16*)ws;             ws += (size_t)NC * NH * 2;          // 2 MB
    bf16* W2T = (bf16*)ws;             ws += (size_t)NH * NC * 2;          // 2 MB
    bf16* Wc1T = (bf16*)ws;            ws += (size_t)NS * NDC * NC * 2;    // 1 MB
    float* style_contrib = (float*)ws; ws += (size_t)NS * NH * 4;          // 32 KB
    float* style_partial = (float*)ws; ws += (size_t)64 * NS * NH * 4;     // 2 MB
    int* sty_cnt   = (int*)ws;         ws += 64;
    int* cursor    = (int*)ws;         ws += 64;
    int* order     = (int*)ws;         ws += (size_t)NB * 4;               // 128 KB
    int* blk_style = (int*)ws;         ws += MAXBLK * 4;
    int* blk_seg0  = (int*)ws;         ws += MAXBLK * 4;
    int* blk_nv    = (int*)ws;         ws += MAXBLK * 4;

    float* adjusted = (float*)d_out;
    float* conf_out = (float*)d_out + (size_t)NB * NC;

    // ---- routing plan (depends only on style_idx) ----
    hipMemsetAsync(sty_cnt, 0, 64, stream);
    hist_kernel<<<NB / 256, 256, 0, stream>>>(style_idx, sty_cnt);
    plan_kernel<<<1, 64, 0, stream>>>(sty_cnt, cursor, blk_style, blk_seg0, blk_nv);
    scatter_kernel<<<NB / 256, 256, 0, stream>>>(style_idx, cursor, order);

    // logits -> bf16
    convert_kernel<<<(NB * NC) / (256 * 8), 256, 0, stream>>>(logits, logits_b);

    dim3 tb(32, 8);
    // W1T[n][k] = Wa1[k][n] (first C rows of Wa1)
    transpose_kernel<<<dim3(32, 32, 1), tb, 0, stream>>>(Wa1, W1T, NC, NH, 0, 0);
    // W2T[n][k] = Wa2[k][n]
    transpose_kernel<<<dim3(32, 32, 1), tb, 0, stream>>>(Wa2, W2T, NH, NC, 0, 0);
    // Wc1T[s*64+d][c] = Wc1[s][c][d]
    transpose_kernel<<<dim3(2, 32, NS), tb, 0, stream>>>(Wc1, Wc1T, NC, NDC,
                                                         (long long)NC * NDC, (long long)NDC * NC);
    // style_contrib = ba1 + style_emb @ Wa1[C:]
    style_partial_kernel<<<256, 256, 0, stream>>>(style_emb, Wa1, style_partial);
    style_reduce_kernel<<<NS * NH / 256, 256, 0, stream>>>(style_partial, ba1, style_contrib);

    // hidden = relu(logits @ Wa1[:C] + style_contrib[style])
    gemm_kernel<0><<<dim3(NH / 128, NB / 128), 256, 0, stream>>>(
        logits_b, W1T, hidden, nullptr, NH, NC, style_contrib, style_idx, nullptr, nullptr);
    // adjusted = logits + hidden @ Wa2 + ba2
    gemm_kernel<1><<<dim3(NC / 128, NB / 128), 256, 0, stream>>>(
        hidden, W2T, nullptr, adjusted, NC, NH, nullptr, nullptr, logits, ba2);
    // probs = softmax(adjusted)  (reuse hidden buffer)
    softmax_kernel<<<NB, 256, 0, stream>>>(adjusted, hidden);
    // conf = sigmoid(relu(probs @ Wc1[s] + bc1[s]) . Wc2[s] + bc2[s]), routed by style
    gemm_cal_kernel<<<MAXBLK, 256, 0, stream>>>(hidden, Wc1T, order, blk_style, blk_seg0,
                                                blk_nv, bc1, Wc2, bc2, conf_out);
}

// Round 3
// 528.041 us; speedup vs baseline: 1.1063x; 1.1063x over previous
//
#include <hip/hip_runtime.h>
#include <hip/hip_bf16.h>
#include <stdint.h>

typedef __hip_bfloat16 bf16;
typedef __attribute__((ext_vector_type(8))) short short8;
typedef __attribute__((ext_vector_type(4))) float f32x4;

#define NB 32768
#define NC 1024
#define NH 1024
#define NS 8
#define NDC 64

__device__ __forceinline__ void gload_lds16(const void* g, void* l) {
    __builtin_amdgcn_global_load_lds((const __attribute__((address_space(1))) void*)g,
                                     (__attribute__((address_space(3))) void*)l, 16, 0, 0);
}

__device__ __forceinline__ short f2bf(float x) {
    bf16 h = __float2bfloat16(x);
    short s;
    __builtin_memcpy(&s, &h, 2);
    return s;
}

// ---------------- fp32 -> bf16 bulk convert (8 elems/thread) ----------------
__global__ __launch_bounds__(256) void convert_kernel(
    const float* __restrict__ in, bf16* __restrict__ out)
{
    const size_t i = ((size_t)blockIdx.x * 256 + threadIdx.x) * 8;
    float4 a = *(const float4*)(in + i);
    float4 b = *(const float4*)(in + i + 4);
    short8 v;
    v[0] = f2bf(a.x); v[1] = f2bf(a.y); v[2] = f2bf(a.z); v[3] = f2bf(a.w);
    v[4] = f2bf(b.x); v[5] = f2bf(b.y); v[6] = f2bf(b.z); v[7] = f2bf(b.w);
    *(short8*)((short*)out + i) = v;
}

// ---------------- batched tiled transpose + downcast: out[c][r] = bf16(in[r][c]) ----------------
__global__ __launch_bounds__(256) void transpose_kernel(
    const float* __restrict__ in, bf16* __restrict__ out,
    int R, int Ccols, long long in_bs, long long out_bs)
{
    __shared__ float tile[32][33];
    const float* inb = in + (long long)blockIdx.z * in_bs;
    bf16* outb = out + (long long)blockIdx.z * out_bs;
    int c0 = blockIdx.x * 32, r0 = blockIdx.y * 32;
    int tx = threadIdx.x, ty = threadIdx.y; // 32 x 8
#pragma unroll
    for (int i = 0; i < 32; i += 8)
        tile[ty + i][tx] = inb[(size_t)(r0 + ty + i) * Ccols + c0 + tx];
    __syncthreads();
#pragma unroll
    for (int i = 0; i < 32; i += 8)
        outb[(size_t)(c0 + ty + i) * R + r0 + tx] = __float2bfloat16(tile[tx][ty + i]);
}

// ---------------- style_contrib split-K stage 1 ----------------
__global__ __launch_bounds__(256) void style_partial_kernel(
    const float* __restrict__ style_emb, const float* __restrict__ Wa1,
    float* __restrict__ partial)
{
    const int h = (blockIdx.x & 3) * 256 + threadIdx.x;
    const int ks = blockIdx.x >> 2;
    float acc[NS];
#pragma unroll
    for (int s = 0; s < NS; ++s) acc[s] = 0.f;
#pragma unroll
    for (int kk = 0; kk < 16; ++kk) {
        const int k = ks * 16 + kk;
        const float w = Wa1[(size_t)(NC + k) * NH + h];
#pragma unroll
        for (int s = 0; s < NS; ++s)
            acc[s] += style_emb[s * NH + k] * w;
    }
#pragma unroll
    for (int s = 0; s < NS; ++s)
        partial[((size_t)ks * NS + s) * NH + h] = acc[s];
}

// ---------------- style_contrib split-K stage 2 ----------------
__global__ __launch_bounds__(256) void style_reduce_kernel(
    const float* __restrict__ partial, const float* __restrict__ ba1,
    float* __restrict__ out)
{
    const int i = blockIdx.x * 256 + threadIdx.x; // 8192 = NS*NH
    const int h = i & (NH - 1);
    const int s = i >> 10;
    float acc = ba1[h];
#pragma unroll 8
    for (int ks = 0; ks < 64; ++ks)
        acc += partial[((size_t)ks * NS + s) * NH + h];
    out[i] = acc;
}

// ---------------- m97-style bf16 GEMM (single-buffer; measured best structure) ----------------
// MODE 0: bf16 out = relu(acc + style_contrib[style_idx[row]][col])     -> hidden
// MODE 1: f32  out = acc + resid[row][col] + bias[col]                  -> adjusted_logits
template<int MODE>
__global__ __launch_bounds__(256, 2) void gemm_kernel(
    const bf16* __restrict__ A, const bf16* __restrict__ BT,
    bf16* __restrict__ Cb, float* __restrict__ Cf,
    int N, int K,
    const float* __restrict__ style_contrib, const int* __restrict__ style_idx,
    const float* __restrict__ resid, const float* __restrict__ bias)
{
    __shared__ short lA[128 * 32];
    __shared__ short lB[128 * 32];

    const int t = threadIdx.x;
    const int lane = t & 63;
    const int wave = t >> 6;
    const int wr = wave >> 1;
    const int wc = wave & 1;

    // T1: XCD-aware bijective swizzle (8 XCDs; nwg divisible by 8).
    const int nwg = gridDim.x * gridDim.y;
    const int flat = blockIdx.y * gridDim.x + blockIdx.x;
    const int cpx = nwg >> 3;
    const int swz = (flat & 7) * cpx + (flat >> 3);
    const int bm0 = (swz / gridDim.x) * 128;
    const int bn0 = (swz % gridDim.x) * 128;

    const int r0 = t >> 2;        // staging row
    const int c8 = (t & 3) * 8;   // staging k-chunk

    const int mrow = lane & 15;
    const int quad = lane >> 4;

    f32x4 acc[4][4];
#pragma unroll
    for (int i = 0; i < 4; ++i)
#pragma unroll
        for (int j = 0; j < 4; ++j) acc[i][j] = (f32x4){0.f, 0.f, 0.f, 0.f};

    const bf16* gA = A + (size_t)(bm0 + r0) * K + c8;
    const bf16* gB = BT + (size_t)(bn0 + r0) * K + c8;

    for (int k0 = 0; k0 < K; k0 += 32) {
        gload_lds16(gA + k0, lA + t * 8);
        gload_lds16(gA + (size_t)64 * K + k0, lA + 2048 + t * 8);
        gload_lds16(gB + k0, lB + t * 8);
        gload_lds16(gB + (size_t)64 * K + k0, lB + 2048 + t * 8);
        __syncthreads();

        short8 af[4], bfr[4];
#pragma unroll
        for (int i = 0; i < 4; ++i)
            af[i] = *(const short8*)(lA + (wr * 64 + i * 16 + mrow) * 32 + quad * 8);
#pragma unroll
        for (int j = 0; j < 4; ++j)
            bfr[j] = *(const short8*)(lB + (wc * 64 + j * 16 + mrow) * 32 + quad * 8);
#pragma unroll
        for (int i = 0; i < 4; ++i)
#pragma unroll
            for (int j = 0; j < 4; ++j)
                acc[i][j] = __builtin_amdgcn_mfma_f32_16x16x32_bf16(af[i], bfr[j], acc[i][j], 0, 0, 0);
        __syncthreads();
    }

    // epilogue: C/D layout col = lane&15, row = quad*4 + reg
#pragma unroll
    for (int i = 0; i < 4; ++i) {
#pragma unroll
        for (int r = 0; r < 4; ++r) {
            const int grow = bm0 + wr * 64 + i * 16 + quad * 4 + r;
            const float* scrow = nullptr;
            const float* resrow = nullptr;
            if (MODE == 0) scrow = style_contrib + (size_t)style_idx[grow] * N;
            if (MODE == 1) resrow = resid + (size_t)grow * N;
#pragma unroll
            for (int j = 0; j < 4; ++j) {
                const int gcol = bn0 + wc * 64 + j * 16 + mrow;
                float v = acc[i][j][r];
                if (MODE == 0) {
                    v += scrow[gcol];
                    v = fmaxf(v, 0.f);
                    Cb[(size_t)grow * N + gcol] = __float2bfloat16(v);
                } else {
                    v += resrow[gcol] + bias[gcol];
                    Cf[(size_t)grow * N + gcol] = v;
                }
            }
        }
    }
}

// ---------------- calibrator GEMM with FUSED conf epilogue ----------------
// Computes hcal = relu(probs @ Wc1T^T + bc1) for all 8 styles (N = 512 = 8*64),
// but never materializes it: each 64-col half of a block covers one complete
// style, so conf = sigmoid(dot(relu(h), Wc2[s]) + bc2[s]) reduces within the
// 16-lane quad group holding that row. Each row's style matches exactly one
// (bn0, wc) -> written exactly once. Eliminates 32MB write + 32MB scattered read.
__global__ __launch_bounds__(256, 2) void gemm_conf_kernel(
    const bf16* __restrict__ A, const bf16* __restrict__ BT,
    int N, int K,
    const int* __restrict__ style_idx,
    const float* __restrict__ bc1, const float* __restrict__ Wc2,
    const float* __restrict__ bc2, float* __restrict__ conf_out)
{
    __shared__ short lA[128 * 32];
    __shared__ short lB[128 * 32];

    const int t = threadIdx.x;
    const int lane = t & 63;
    const int wave = t >> 6;
    const int wr = wave >> 1;
    const int wc = wave & 1;

    // T1 swizzle (nwg = 4*256 = 1024, divisible by 8)
    const int nwg = gridDim.x * gridDim.y;
    const int flat = blockIdx.y * gridDim.x + blockIdx.x;
    const int cpx = nwg >> 3;
    const int swz = (flat & 7) * cpx + (flat >> 3);
    const int bm0 = (swz / gridDim.x) * 128;
    const int bn0 = (swz % gridDim.x) * 128;

    const int r0 = t >> 2;
    const int c8 = (t & 3) * 8;

    const int mrow = lane & 15;
    const int quad = lane >> 4;

    f32x4 acc[4][4];
#pragma unroll
    for (int i = 0; i < 4; ++i)
#pragma unroll
        for (int j = 0; j < 4; ++j) acc[i][j] = (f32x4){0.f, 0.f, 0.f, 0.f};

    const bf16* gA = A + (size_t)(bm0 + r0) * K + c8;
    const bf16* gB = BT + (size_t)(bn0 + r0) * K + c8;

    for (int k0 = 0; k0 < K; k0 += 32) {
        gload_lds16(gA + k0, lA + t * 8);
        gload_lds16(gA + (size_t)64 * K + k0, lA + 2048 + t * 8);
        gload_lds16(gB + k0, lB + t * 8);
        gload_lds16(gB + (size_t)64 * K + k0, lB + 2048 + t * 8);
        __syncthreads();

        short8 af[4], bfr[4];
#pragma unroll
        for (int i = 0; i < 4; ++i)
            af[i] = *(const short8*)(lA + (wr * 64 + i * 16 + mrow) * 32 + quad * 8);
#pragma unroll
        for (int j = 0; j < 4; ++j)
            bfr[j] = *(const short8*)(lB + (wc * 64 + j * 16 + mrow) * 32 + quad * 8);
#pragma unroll
        for (int i = 0; i < 4; ++i)
#pragma unroll
            for (int j = 0; j < 4; ++j)
                acc[i][j] = __builtin_amdgcn_mfma_f32_16x16x32_bf16(af[i], bfr[j], acc[i][j], 0, 0, 0);
        __syncthreads();
    }

    // this wave-half covers style s_w completely (cols s_w*64 .. s_w*64+63)
    const int s_w = (bn0 >> 6) + wc;
    float bcv[4], wcv[4];
#pragma unroll
    for (int j = 0; j < 4; ++j) {
        const int d = j * 16 + mrow;
        bcv[j] = bc1[s_w * NDC + d];
        wcv[j] = Wc2[s_w * NDC + d];
    }
    const float bias2 = bc2[s_w];

#pragma unroll
    for (int i = 0; i < 4; ++i) {
#pragma unroll
        for (int r = 0; r < 4; ++r) {
            const int grow = bm0 + wr * 64 + i * 16 + quad * 4 + r;
            float p = 0.f;
#pragma unroll
            for (int j = 0; j < 4; ++j)
                p += fmaxf(acc[i][j][r] + bcv[j], 0.f) * wcv[j];
            // reduce across the 16 lanes (mrow) of this quad group
#pragma unroll
            for (int off = 1; off < 16; off <<= 1) p += __shfl_xor(p, off, 64);
            if (mrow == 0 && style_idx[grow] == s_w)
                conf_out[grow] = 1.0f / (1.0f + __expf(-(p + bias2)));
        }
    }
}

// ---------------- row softmax (1024 cols), f32 in -> bf16 out ----------------
__global__ __launch_bounds__(256) void softmax_kernel(
    const float* __restrict__ in, bf16* __restrict__ out)
{
    const size_t row = blockIdx.x;
    const float* x = in + row * NC;
    bf16* o = out + row * NC;
    const int t = threadIdx.x;
    __shared__ float red[8];

    float v[4];
    float m = -1e30f;
#pragma unroll
    for (int i = 0; i < 4; ++i) {
        v[i] = x[t + i * 256];
        m = fmaxf(m, v[i]);
    }
#pragma unroll
    for (int off = 1; off < 64; off <<= 1) m = fmaxf(m, __shfl_xor(m, off, 64));
    const int wv = t >> 6;
    if ((t & 63) == 0) red[wv] = m;
    __syncthreads();
    const float gm = fmaxf(fmaxf(red[0], red[1]), fmaxf(red[2], red[3]));

    float s = 0.f;
#pragma unroll
    for (int i = 0; i < 4; ++i) {
        v[i] = __expf(v[i] - gm);
        s += v[i];
    }
#pragma unroll
    for (int off = 1; off < 64; off <<= 1) s += __shfl_xor(s, off, 64);
    if ((t & 63) == 0) red[4 + wv] = s;
    __syncthreads();
    const float inv = 1.0f / (red[4] + red[5] + red[6] + red[7]);
#pragma unroll
    for (int i = 0; i < 4; ++i) o[t + i * 256] = __float2bfloat16(v[i] * inv);
}

extern "C" void kernel_launch(void* const* d_in, const int* in_sizes, int n_in,
                              void* d_out, int out_size, void* d_ws, size_t ws_size,
                              hipStream_t stream) {
    const float* logits    = (const float*)d_in[0];
    const int*   style_idx = (const int*)d_in[1];
    const float* style_emb = (const float*)d_in[2];
    const float* Wa1       = (const float*)d_in[3];
    const float* ba1       = (const float*)d_in[4];
    const float* Wa2       = (const float*)d_in[5];
    const float* ba2       = (const float*)d_in[6];
    const float* Wc1       = (const float*)d_in[7];
    const float* bc1       = (const float*)d_in[8];
    const float* Wc2       = (const float*)d_in[9];
    const float* bc2       = (const float*)d_in[10];

    char* ws = (char*)d_ws;
    bf16* logits_b = (bf16*)ws;        ws += (size_t)NB * NC * 2;          // 64 MB
    bf16* hidden = (bf16*)ws;          ws += (size_t)NB * NH * 2;          // 64 MB (reused as probs)
    bf16* W1T = (bf16*)ws;             ws += (size_t)NC * NH * 2;          // 2 MB
    bf16* W2T = (bf16*)ws;             ws += (size_t)NH * NC * 2;          // 2 MB
    bf16* Wc1T = (bf16*)ws;            ws += (size_t)NS * NDC * NC * 2;    // 1 MB
    float* style_contrib = (float*)ws; ws += (size_t)NS * NH * 4;          // 32 KB
    float* style_partial = (float*)ws; ws += (size_t)64 * NS * NH * 4;     // 2 MB

    float* adjusted = (float*)d_out;
    float* conf_out = (float*)d_out + (size_t)NB * NC;

    // logits -> bf16
    convert_kernel<<<(NB * NC) / (256 * 8), 256, 0, stream>>>(logits, logits_b);

    dim3 tb(32, 8);
    // W1T[n][k] = Wa1[k][n] (first C rows of Wa1)
    transpose_kernel<<<dim3(32, 32, 1), tb, 0, stream>>>(Wa1, W1T, NC, NH, 0, 0);
    // W2T[n][k] = Wa2[k][n]
    transpose_kernel<<<dim3(32, 32, 1), tb, 0, stream>>>(Wa2, W2T, NH, NC, 0, 0);
    // Wc1T[s*64+d][c] = Wc1[s][c][d]
    transpose_kernel<<<dim3(2, 32, NS), tb, 0, stream>>>(Wc1, Wc1T, NC, NDC,
                                                         (long long)NC * NDC, (long long)NDC * NC);
    // style_contrib = ba1 + style_emb @ Wa1[C:]
    style_partial_kernel<<<256, 256, 0, stream>>>(style_emb, Wa1, style_partial);
    style_reduce_kernel<<<NS * NH / 256, 256, 0, stream>>>(style_partial, ba1, style_contrib);

    // hidden = relu(logits @ Wa1[:C] + style_contrib[style])
    gemm_kernel<0><<<dim3(NH / 128, NB / 128), 256, 0, stream>>>(
        logits_b, W1T, hidden, nullptr, NH, NC, style_contrib, style_idx, nullptr, nullptr);
    // adjusted = logits + hidden @ Wa2 + ba2
    gemm_kernel<1><<<dim3(NC / 128, NB / 128), 256, 0, stream>>>(
        hidden, W2T, nullptr, adjusted, NC, NH, nullptr, nullptr, logits, ba2);
    // probs = softmax(adjusted)  (reuse hidden buffer)
    softmax_kernel<<<NB, 256, 0, stream>>>(adjusted, hidden);
    // conf = sigmoid(relu(probs @ Wc1 + bc1) . Wc2 + bc2), conf fused in epilogue
    gemm_conf_kernel<<<dim3((NS * NDC) / 128, NB / 128), 256, 0, stream>>>(
        hidden, Wc1T, NS * NDC, NC, style_idx, bc1, Wc2, bc2, conf_out);
}